// Round 8
// baseline (146.539 us; speedup 1.0000x reference)
//
#include <hip/hip_runtime.h>

// y = x @ W_base^T + b + S * adapter(x);  adapter folds into the weight:
//   W_eff[o*64+e][i*64+d] = W_base[..] + S * U[d,i,o] * V[o,d,e]
// => one bf16 GEMM  C[4096][4096] = Xb @ W_eff^T + bias
// GEMM: round-3 structure (256x256, BK=64, 8 waves, mfma 16x16x32,
// 4 phases/tile, 1 barrier/phase, 0-conflict swizzle) with deepened stage
// cadence: Ah0(t+1)@(t-1).P3, Ah1(t+1)@t.P0, B(t+2)@t.P2/P3 -> vmcnt(6)/tile.

typedef __attribute__((ext_vector_type(4))) float  float4v;
typedef __attribute__((ext_vector_type(8))) __bf16 bf16x8;
typedef __attribute__((ext_vector_type(4))) short  short4v;

#define K_TOT 4096
#define M_TOT 4096
#define N_TOT 4096

__device__ __forceinline__ unsigned short f2bf(float f) {
  unsigned int u = __float_as_uint(f);
  u += 0x7FFFu + ((u >> 16) & 1u);
  return (unsigned short)(u >> 16);
}

// ------------- tiny transposes: Ut[i][o][d]=U[d][i][o], Vt[o][e][d]=V[o][d][e]
__global__ void trans_uv(const float* __restrict__ U, const float* __restrict__ V,
                         float* __restrict__ Ut, float* __restrict__ Vt) {
  int idx = blockIdx.x * 256 + threadIdx.x;
  if (idx < 262144) {
    int d = idx & 63, o = (idx >> 6) & 63, i = idx >> 12;
    Ut[idx] = U[(d * 64 + i) * 64 + o];
  } else {
    int j = idx - 262144;
    int d = j & 63, e = (j >> 6) & 63, o = j >> 12;
    Vt[j] = V[(o * 64 + d) * 64 + e];
  }
}

// ------------- fused prep: W_eff = bf16(W + S*Ut*Vt);  Xb = bf16(X) ---------
__global__ void prep_all(const float* __restrict__ W, const float* __restrict__ Ut,
                         const float* __restrict__ Vt, const float* __restrict__ Sp,
                         const float* __restrict__ X,
                         unsigned short* __restrict__ Weff,
                         unsigned short* __restrict__ Xb) {
  const float s = Sp[0];
  const int wq = (N_TOT * K_TOT) / 4;
  const int total4 = wq + (M_TOT * K_TOT) / 4;
  for (int idx = blockIdx.x * 256 + threadIdx.x; idx < total4;
       idx += gridDim.x * 256) {
    if (idx < wq) {
      const int base = idx << 2;
      const int of = base >> 12, if0 = base & 4095;
      const int o = of >> 6, e = of & 63, i = if0 >> 6, d0 = if0 & 63;
      const float4v wv = *(const float4v*)(W + (size_t)base);
      const float4v u4 = *(const float4v*)(Ut + (i * 64 + o) * 64 + d0);
      const float4v v4 = *(const float4v*)(Vt + (o * 64 + e) * 64 + d0);
      short4v pk;
#pragma unroll
      for (int j = 0; j < 4; ++j) pk[j] = (short)f2bf(wv[j] + s * u4[j] * v4[j]);
      *(short4v*)(Weff + (size_t)base) = pk;
    } else {
      const int base = (idx - wq) << 2;
      const float4v v = *(const float4v*)(X + (size_t)base);
      short4v pk;
#pragma unroll
      for (int j = 0; j < 4; ++j) pk[j] = (short)f2bf(v[j]);
      *(short4v*)(Xb + (size_t)base) = pk;
    }
  }
}

// ---------------- 256x256 8-phase GEMM --------------------------------------
#define GL16(g, l)                                                    \
  __builtin_amdgcn_global_load_lds(                                   \
      (__attribute__((address_space(1))) void*)(g),                   \
      (__attribute__((address_space(3))) void*)(l), 16, 0, 0)

#define BARRIER() asm volatile("s_barrier" ::: "memory")
#define VMC6() asm volatile("s_waitcnt vmcnt(6)" ::: "memory")
#define VMC0() asm volatile("s_waitcnt vmcnt(0)" ::: "memory")
#define VMNONE()

__global__ __launch_bounds__(512, 2) void gemm256(
    const unsigned short* __restrict__ A,    // [4096][4096] bf16 (X)
    const unsigned short* __restrict__ Bm,   // [4096][4096] bf16 (W_eff)
    const float* __restrict__ bias,
    float* __restrict__ C) {
  // [buf][op A=0/B=1][row-half][128 rows][64 cols bf16] = 128 KiB
  __shared__ unsigned short lds[2][2][2][8192];

  const int tid = threadIdx.x;
  const int w = tid >> 6;
  const int l = tid & 63;
  const int l15 = l & 15;
  const int hi = l >> 4;

  // XCD-aware bijective swizzle (256 blocks, 256 % 8 == 0)
  int b = blockIdx.x;
  b = (b & 7) * 32 + (b >> 3);
  const int brow = (b >> 4) * 256;
  const int bcol = (b & 15) * 256;

  const int wr = w >> 2;        // 0..1 -> 128-row half of A-tile
  const int wc = w & 3;         // 0..3 -> 64-row slice of B-tile
  const int wcH = wc >> 1, wcL = wc & 1;

  // read-side T2 swizzle: logical chunk (kk*4 + hi) ^ (row&7), row%16 == l15
  const int b2 = (l15 >> 2) & 1;
  const int cx = hi ^ (l15 & 3);
  const int rdK0 = (((b2 ^ 0) << 2) | cx) << 3;   // kk=0 chunk offset (ushorts)
  const int rdK1 = (((b2 ^ 1) << 2) | cx) << 3;   // kk=1
  const int rowOff = l15 << 6;                    // l15 * 64 ushorts

  // stage-side inverse: lane covers phys chunk (w*64 + l); row = w*8 + (l>>3)
  const int rowL = l >> 3;
  const int cL = (l & 7) ^ rowL;
  const unsigned short* pa = A + (size_t)(brow + w * 8 + rowL) * K_TOT + cL * 8;
  const unsigned short* pb = Bm + (size_t)(bcol + w * 8 + rowL) * K_TOT + cL * 8;
  const int ldsC0 = (w * 64) * 8;        // wave chunk base, rows 0-63 of half
  const int ldsC1 = (512 + w * 64) * 8;  // rows 64-127

#define STAGE(gp, BUF, OP, H, kt)                                             \
  do {                                                                        \
    GL16((gp) + (size_t)(H) * (128 * K_TOT) + (kt), &lds[BUF][OP][H][ldsC0]); \
    GL16((gp) + (size_t)(H) * (128 * K_TOT) + (64 * K_TOT) + (kt),            \
         &lds[BUF][OP][H][ldsC1]);                                            \
  } while (0)

  float4v acc[8][4];
#pragma unroll
  for (int m = 0; m < 8; ++m)
#pragma unroll
    for (int j = 0; j < 4; ++j) acc[m][j] = (float4v){0.f, 0.f, 0.f, 0.f};
  bf16x8 af[4][2];    // A frags: 4 m-rows x 2 kk
  bf16x8 bfr[4][2];   // B frags: 4 n x 2 kk (live whole tile)

#define READ_A(BUF, MB)                                                     \
  _Pragma("unroll") for (int mm = 0; mm < 4; ++mm) {                        \
    const unsigned short* ap =                                              \
        &lds[BUF][0][wr][((MB) + mm) * 1024 + rowOff];                      \
    af[mm][0] = *(const bf16x8*)&ap[rdK0];                                  \
    af[mm][1] = *(const bf16x8*)&ap[rdK1];                                  \
  }

#define READ_B(BUF, NH)                                                     \
  _Pragma("unroll") for (int jj = 0; jj < 2; ++jj) {                        \
    const unsigned short* bp =                                              \
        &lds[BUF][1][wcH]                                                   \
            [((wcL)*64 + (NH)*32 + jj * 16) * 64 + rowOff];                 \
    bfr[(NH)*2 + jj][0] = *(const bf16x8*)&bp[rdK0];                        \
    bfr[(NH)*2 + jj][1] = *(const bf16x8*)&bp[rdK1];                        \
  }

#define MFMA16(MB, NB)                                                      \
  do {                                                                      \
    __builtin_amdgcn_s_setprio(1);                                          \
    _Pragma("unroll") for (int mm = 0; mm < 4; ++mm)                        \
        _Pragma("unroll") for (int nn = 0; nn < 2; ++nn) {                  \
      acc[(MB) + mm][(NB) + nn] = __builtin_amdgcn_mfma_f32_16x16x32_bf16(  \
          af[mm][0], bfr[(NB) + nn][0], acc[(MB) + mm][(NB) + nn], 0, 0, 0);\
      acc[(MB) + mm][(NB) + nn] = __builtin_amdgcn_mfma_f32_16x16x32_bf16(  \
          af[mm][1], bfr[(NB) + nn][1], acc[(MB) + mm][(NB) + nn], 0, 0, 0);\
    }                                                                       \
    __builtin_amdgcn_s_setprio(0);                                          \
  } while (0)

  // Cadence (race-free, ledger-verified):
  //   P0: stage Ah1(t+1)->buf^1 (A(t-1) last read (t-1).P2, 2 barriers prior)
  //   P2: stage Bh0(t+2)->buf   (B(t) last read t.P1)
  //   P3: stage Bh1(t+2)->buf, Ah0(t+2)->buf (A(t) last read t.P2); vmcnt(6)
  // Invariant after each P3 wait: exactly {Bh0,Bh1,Ah0}(t+2) = 6 loads in
  // flight, tile t+1 fully landed.
#define TILE(BUF, TT, DA1, DB, DA0, VM)                                    \
  do {                                                                     \
    READ_A(BUF, 0); READ_B(BUF, 0);                                        \
    if (DA1) STAGE(pa, 1 - (BUF), 0, 1, ((TT) + 1) * 64);                  \
    BARRIER(); MFMA16(0, 0);                                               \
    READ_B(BUF, 1);                                                        \
    BARRIER(); MFMA16(0, 2);                                               \
    READ_A(BUF, 4);                                                        \
    if (DB) STAGE(pb, BUF, 1, 0, ((TT) + 2) * 64);                         \
    BARRIER(); MFMA16(4, 0);                                               \
    if (DB) STAGE(pb, BUF, 1, 1, ((TT) + 2) * 64);                         \
    if (DA0) STAGE(pa, BUF, 0, 0, ((TT) + 2) * 64);                        \
    VM();                                                                  \
    BARRIER(); MFMA16(4, 2);                                               \
  } while (0)

  // prologue: tile0 {Ah0,Ah1,Bh0,Bh1}, tile1 {Bh0,Bh1,Ah0}; retire tile0's 8,
  // leaving the 6-load invariant. Ah1(1) is staged at loop t=0 P0.
  STAGE(pa, 0, 0, 0, 0);
  STAGE(pa, 0, 0, 1, 0);
  STAGE(pb, 0, 1, 0, 0);
  STAGE(pb, 0, 1, 1, 0);
  STAGE(pb, 1, 1, 0, 64);
  STAGE(pb, 1, 1, 1, 64);
  STAGE(pa, 1, 0, 0, 64);
  VMC6();
  BARRIER();

  for (int t = 0; t < 62; t += 2) {
    TILE(0, t, 1, 1, 1, VMC6);
    TILE(1, t + 1, 1, 1, 1, VMC6);
  }
  TILE(0, 62, 1, 0, 0, VMC0);   // stages Ah1(63) only; drain everything
  TILE(1, 63, 0, 0, 0, VMNONE); // nothing staged, nothing waited

  // epilogue: C/D layout col = lane&15, row = (lane>>4)*4 + v
  const int r0 = brow + wr * 128 + (l >> 4) * 4;
  const int c0 = bcol + wc * 64;
#pragma unroll
  for (int j = 0; j < 4; ++j) {
    const int col = c0 + j * 16 + l15;
    const float bv = bias[col];
#pragma unroll
    for (int m = 0; m < 8; ++m) {
      const int row = r0 + m * 16;
#pragma unroll
      for (int v = 0; v < 4; ++v)
        C[(size_t)(row + v) * N_TOT + col] = acc[m][j][v] + bv;
    }
  }
}

extern "C" void kernel_launch(void* const* d_in, const int* in_sizes, int n_in,
                              void* d_out, int out_size, void* d_ws, size_t ws_size,
                              hipStream_t stream) {
  const float* x = (const float*)d_in[0];    // [2,2048,4096]
  const float* Wb = (const float*)d_in[1];   // [4096,4096]
  const float* bb = (const float*)d_in[2];   // [4096]
  const float* U = (const float*)d_in[3];    // [64,64,64]
  const float* V = (const float*)d_in[4];    // [64,64,64]
  const float* S = (const float*)d_in[5];    // [1]
  float* out = (float*)d_out;

  unsigned short* Weff = (unsigned short*)d_ws;                     // 32 MiB
  unsigned short* Xb =
      (unsigned short*)((char*)d_ws + (size_t)N_TOT * K_TOT * 2);   // 32 MiB
  // Ut/Vt scratch in d_out's head (1 MiB each) — overwritten by the GEMM later
  float* Ut = (float*)d_out;
  float* Vt = Ut + 262144;

  trans_uv<<<2048, 256, 0, stream>>>(U, V, Ut, Vt);
  prep_all<<<4096, 256, 0, stream>>>(Wb, Ut, Vt, S, x, Weff, Xb);

  gemm256<<<256, 512, 0, stream>>>(Xb, Weff, bb, out);
}

// Round 9
// 102.080 us; speedup vs baseline: 1.4355x; 1.4355x over previous
//
#include <hip/hip_runtime.h>

// y = x @ W_base^T + b + S * adapter(x);  adapter folds into the weight:
//   W_eff[o*64+e][i*64+d] = W_base[..] + S * U[d,i,o] * V[o,d,e]
// This round: int8 GEMM. Per-row symmetric quantization of X and W_eff
// (scales sx[m], sw[n]); y = sx[m]*sw[n]*(i32 acc) + bias.
// GEMM geometry is byte-identical to the proven round-3/7 bf16 kernel
// (256x256 tile, rows of 128B = 8 chunks, same 0-conflict swizzle, same
// 4-phase/tile cadence, vmcnt(6)) but BK=128 i8 -> 32 K-tiles instead of 64.

typedef __attribute__((ext_vector_type(4))) float float4v;
typedef __attribute__((ext_vector_type(4))) int   int4v;

#define K_TOT 4096
#define M_TOT 4096
#define N_TOT 4096

// ------------- tiny transposes: Ut[i][o][d]=U[d][i][o], Vt[o][e][d]=V[o][d][e]
__global__ void trans_uv(const float* __restrict__ U, const float* __restrict__ V,
                         float* __restrict__ Ut, float* __restrict__ Vt) {
  int idx = blockIdx.x * 256 + threadIdx.x;
  if (idx < 262144) {
    int d = idx & 63, o = (idx >> 6) & 63, i = idx >> 12;
    Ut[idx] = U[(d * 64 + i) * 64 + o];
  } else {
    int j = idx - 262144;
    int d = j & 63, e = (j >> 6) & 63, o = j >> 12;
    Vt[j] = V[(o * 64 + d) * 64 + e];
  }
}

// ------------- fused quantize: one block per row -----------------------------
// rows 0..4095   : W_eff row (computed on the fly) -> Wq + sw[row]
// rows 4096..8191: X row                           -> Xq + sx[row-4096]
__global__ __launch_bounds__(1024) void quant_rows(
    const float* __restrict__ W, const float* __restrict__ Ut,
    const float* __restrict__ Vt, const float* __restrict__ Sp,
    const float* __restrict__ X, char* __restrict__ Wq, char* __restrict__ Xq,
    float* __restrict__ sw, float* __restrict__ sx) {
  __shared__ float red[16];
  const int row = blockIdx.x;
  const int t = threadIdx.x;          // 0..1023, one 16B quad each
  const float s = Sp[0];
  float4v v;
  if (row < 4096) {
    const int o = row >> 6, e = row & 63;
    const int i = t >> 4, d0 = (t & 15) << 2;
    const float4v wv = *(const float4v*)(W + (size_t)row * 4096 + t * 4);
    const float4v u4 = *(const float4v*)(Ut + (i * 64 + o) * 64 + d0);
    const float4v v4 = *(const float4v*)(Vt + (o * 64 + e) * 64 + d0);
#pragma unroll
    for (int j = 0; j < 4; ++j) v[j] = wv[j] + s * u4[j] * v4[j];
  } else {
    v = *(const float4v*)(X + (size_t)(row - 4096) * 4096 + t * 4);
  }
  float m = fmaxf(fmaxf(fabsf(v[0]), fabsf(v[1])),
                  fmaxf(fabsf(v[2]), fabsf(v[3])));
#pragma unroll
  for (int off = 32; off; off >>= 1) m = fmaxf(m, __shfl_xor(m, off));
  if ((t & 63) == 0) red[t >> 6] = m;
  __syncthreads();
  if (t < 16) {
    float mm = red[t];
#pragma unroll
    for (int off = 8; off; off >>= 1) mm = fmaxf(mm, __shfl_xor(mm, off));
    if (t == 0) red[0] = mm;
  }
  __syncthreads();
  const float mx = red[0];
  const float inv = mx > 0.f ? 127.f / mx : 0.f;
  int q[4];
#pragma unroll
  for (int j = 0; j < 4; ++j) {
    int qi = __float2int_rn(v[j] * inv);
    q[j] = qi > 127 ? 127 : (qi < -127 ? -127 : qi);
  }
  const int packed = (q[0] & 0xff) | ((q[1] & 0xff) << 8) |
                     ((q[2] & 0xff) << 16) | (q[3] << 24);
  if (row < 4096) {
    ((int*)Wq)[(size_t)row * 1024 + t] = packed;
    if (t == 0) sw[row] = mx * (1.f / 127.f);
  } else {
    ((int*)Xq)[(size_t)(row - 4096) * 1024 + t] = packed;
    if (t == 0) sx[row - 4096] = mx * (1.f / 127.f);
  }
}

// ---------------- 256x256 i8 GEMM (round-3 byte-identical structure) --------
#define GL16(g, l)                                                    \
  __builtin_amdgcn_global_load_lds(                                   \
      (__attribute__((address_space(1))) void*)(g),                   \
      (__attribute__((address_space(3))) void*)(l), 16, 0, 0)

#define BARRIER() asm volatile("s_barrier" ::: "memory")
#define VMC6() asm volatile("s_waitcnt vmcnt(6)" ::: "memory")
#define VMC0() asm volatile("s_waitcnt vmcnt(0)" ::: "memory")
#define VMNONE()

__global__ __launch_bounds__(512, 2) void gemm256(
    const char* __restrict__ A,     // [4096][4096] i8 (Xq)
    const char* __restrict__ Bq,    // [4096][4096] i8 (Wq)
    const float* __restrict__ bias,
    const float* __restrict__ sx,   // [4096] row scales of X
    const float* __restrict__ sw,   // [4096] row scales of W_eff
    float* __restrict__ C) {
  // [buf][op A=0/B=1][row-half][128 rows][128 i8] = 128 KiB
  __shared__ char lds[2][2][2][16384];

  const int tid = threadIdx.x;
  const int w = tid >> 6;
  const int l = tid & 63;
  const int l15 = l & 15;
  const int hi = l >> 4;

  // XCD-aware bijective swizzle (256 blocks, 256 % 8 == 0)
  int b = blockIdx.x;
  b = (b & 7) * 32 + (b >> 3);
  const int brow = (b >> 4) * 256;
  const int bcol = (b & 15) * 256;

  const int wr = w >> 2;        // 0..1 -> 128-row half of A-tile
  const int wc = w & 3;         // 0..3 -> 64-row slice of B-tile
  const int wcH = wc >> 1, wcL = wc & 1;

  // read-side swizzle (byte-identical to round 3, measured 0 conflicts):
  // logical chunk (kk*4 + hi) ^ (row&7), 16B chunks, row%16 == l15
  const int b2 = (l15 >> 2) & 1;
  const int cx = hi ^ (l15 & 3);
  const int rdK0 = (((b2 ^ 0) << 2) | cx) << 4;   // kk=0 chunk byte offset
  const int rdK1 = (((b2 ^ 1) << 2) | cx) << 4;   // kk=1
  const int rowOff = l15 << 7;                    // l15 * 128 bytes

  // stage-side inverse: lane covers phys chunk (w*64 + l); row = w*8 + (l>>3)
  const int rowL = l >> 3;
  const int cL = (l & 7) ^ rowL;
  const char* pa = A + (size_t)(brow + w * 8 + rowL) * 4096 + cL * 16;
  const char* pb = Bq + (size_t)(bcol + w * 8 + rowL) * 4096 + cL * 16;
  const int ldsC0 = w * 1024;          // byte base, rows 0-63 of half
  const int ldsC1 = 8192 + w * 1024;   // rows 64-127

#define STAGE(gp, BUF, OP, H, kt)                                           \
  do {                                                                      \
    GL16((gp) + (size_t)(H) * (128 * 4096) + (kt), &lds[BUF][OP][H][ldsC0]);\
    GL16((gp) + (size_t)(H) * (128 * 4096) + (64 * 4096) + (kt),            \
         &lds[BUF][OP][H][ldsC1]);                                          \
  } while (0)

  int4v acc[8][4];
#pragma unroll
  for (int m = 0; m < 8; ++m)
#pragma unroll
    for (int j = 0; j < 4; ++j) acc[m][j] = (int4v){0, 0, 0, 0};
  int4v af[4][2];    // A frags: 4 m-rows x 2 kk (16 i8 each)
  int4v bfr[4][2];   // B frags: 4 n x 2 kk (live whole tile)

#define READ_A(BUF, MB)                                                     \
  _Pragma("unroll") for (int mm = 0; mm < 4; ++mm) {                        \
    const char* ap = &lds[BUF][0][wr][((MB) + mm) * 2048 + rowOff];         \
    af[mm][0] = *(const int4v*)&ap[rdK0];                                   \
    af[mm][1] = *(const int4v*)&ap[rdK1];                                   \
  }

#define READ_B(BUF, NH)                                                     \
  _Pragma("unroll") for (int jj = 0; jj < 2; ++jj) {                        \
    const char* bp =                                                        \
        &lds[BUF][1][wcH][((wcL)*64 + (NH)*32 + jj * 16) * 128 + rowOff];   \
    bfr[(NH)*2 + jj][0] = *(const int4v*)&bp[rdK0];                         \
    bfr[(NH)*2 + jj][1] = *(const int4v*)&bp[rdK1];                         \
  }

#define MFMA16(MB, NB)                                                      \
  do {                                                                      \
    __builtin_amdgcn_s_setprio(1);                                          \
    _Pragma("unroll") for (int mm = 0; mm < 4; ++mm)                        \
        _Pragma("unroll") for (int nn = 0; nn < 2; ++nn) {                  \
      acc[(MB) + mm][(NB) + nn] = __builtin_amdgcn_mfma_i32_16x16x64_i8(    \
          af[mm][0], bfr[(NB) + nn][0], acc[(MB) + mm][(NB) + nn], 0, 0, 0);\
      acc[(MB) + mm][(NB) + nn] = __builtin_amdgcn_mfma_i32_16x16x64_i8(    \
          af[mm][1], bfr[(NB) + nn][1], acc[(MB) + mm][(NB) + nn], 0, 0, 0);\
    }                                                                       \
    __builtin_amdgcn_s_setprio(0);                                          \
  } while (0)

  // Cadence identical to round 7 (ledger-verified, race-free):
  //   P0: stage Ah1(t+1)->buf^1; P2: Bh0(t+2)->buf;
  //   P3: Bh1(t+2)+Ah0(t+2)->buf, vmcnt(6).
#define TILE(BUF, TT, DA1, DB, DA0, VM)                                    \
  do {                                                                     \
    READ_A(BUF, 0); READ_B(BUF, 0);                                        \
    if (DA1) STAGE(pa, 1 - (BUF), 0, 1, ((TT) + 1) * 128);                 \
    BARRIER(); MFMA16(0, 0);                                               \
    READ_B(BUF, 1);                                                        \
    BARRIER(); MFMA16(0, 2);                                               \
    READ_A(BUF, 4);                                                        \
    if (DB) STAGE(pb, BUF, 1, 0, ((TT) + 2) * 128);                        \
    BARRIER(); MFMA16(4, 0);                                               \
    if (DB) STAGE(pb, BUF, 1, 1, ((TT) + 2) * 128);                        \
    if (DA0) STAGE(pa, BUF, 0, 0, ((TT) + 2) * 128);                       \
    VM();                                                                  \
    BARRIER(); MFMA16(4, 2);                                               \
  } while (0)

  // prologue: tile0 {Ah0,Ah1,Bh0,Bh1}, tile1 {Bh0,Bh1,Ah0}; retire tile0's 8.
  STAGE(pa, 0, 0, 0, 0);
  STAGE(pa, 0, 0, 1, 0);
  STAGE(pb, 0, 1, 0, 0);
  STAGE(pb, 0, 1, 1, 0);
  STAGE(pb, 1, 1, 0, 128);
  STAGE(pb, 1, 1, 1, 128);
  STAGE(pa, 1, 0, 0, 128);
  VMC6();
  BARRIER();

  for (int t = 0; t < 30; t += 2) {
    TILE(0, t, 1, 1, 1, VMC6);
    TILE(1, t + 1, 1, 1, 1, VMC6);
  }
  TILE(0, 30, 1, 0, 0, VMC0);   // stages Ah1(31) only; drain everything
  TILE(1, 31, 0, 0, 0, VMNONE); // nothing staged, nothing waited

  // epilogue: C/D layout (shape-determined): col = lane&15, row=(lane>>4)*4+v
  const int r0 = brow + wr * 128 + (l >> 4) * 4;
  const int c0 = bcol + wc * 64;
  float sxr[8][4];
#pragma unroll
  for (int m = 0; m < 8; ++m)
#pragma unroll
    for (int v = 0; v < 4; ++v) sxr[m][v] = sx[r0 + m * 16 + v];
#pragma unroll
  for (int j = 0; j < 4; ++j) {
    const int col = c0 + j * 16 + l15;
    const float bv = bias[col];
    const float swc = sw[col];
#pragma unroll
    for (int m = 0; m < 8; ++m) {
      const int row = r0 + m * 16;
#pragma unroll
      for (int v = 0; v < 4; ++v)
        C[(size_t)(row + v) * N_TOT + col] =
            (float)acc[m][j][v] * (sxr[m][v] * swc) + bv;
    }
  }
}

extern "C" void kernel_launch(void* const* d_in, const int* in_sizes, int n_in,
                              void* d_out, int out_size, void* d_ws, size_t ws_size,
                              hipStream_t stream) {
  const float* x = (const float*)d_in[0];    // [2,2048,4096]
  const float* Wb = (const float*)d_in[1];   // [4096,4096]
  const float* bb = (const float*)d_in[2];   // [4096]
  const float* U = (const float*)d_in[3];    // [64,64,64]
  const float* V = (const float*)d_in[4];    // [64,64,64]
  const float* S = (const float*)d_in[5];    // [1]
  float* out = (float*)d_out;

  char* Wq = (char*)d_ws;                               // 16 MiB
  char* Xq = Wq + (size_t)4096 * 4096;                  // 16 MiB
  float* sw = (float*)(Xq + (size_t)4096 * 4096);       // 16 KiB
  float* sx = sw + 4096;                                // 16 KiB
  // Ut/Vt scratch in d_out's head (1 MiB each) — overwritten by the GEMM later
  float* Ut = (float*)d_out;
  float* Vt = Ut + 262144;

  trans_uv<<<2048, 256, 0, stream>>>(U, V, Ut, Vt);
  quant_rows<<<8192, 1024, 0, stream>>>(Wb, Ut, Vt, S, x, Wq, Xq, sw, sx);

  gemm256<<<256, 512, 0, stream>>>(Xq, Wq, bb, sx, sw, out);
}